// Round 6
// baseline (397.989 us; speedup 1.0000x reference)
//
#include <hip/hip_runtime.h>
#include <hip/hip_bf16.h>

// Problem: B=2, T=2048, D=2048, H=16, HD=128.
// Inputs fp32, output fp32. Compute via bf16 MFMA, fp32 acc.
#define B_ 2
#define T_ 2048
#define D_ 2048
#define H_ 16
#define HD_ 128
#define N3_ (3 * D_)
#define M_ (B_ * T_)
#define GKD 2048

typedef __attribute__((ext_vector_type(8))) short short8;   // 8 x bf16
typedef __attribute__((ext_vector_type(4))) short short4v;  // 4 x bf16 (8 B)
typedef __attribute__((ext_vector_type(4))) float floatx4;  // 4 x fp32 acc

// round-to-nearest-even f32 -> bf16 bits
__device__ __forceinline__ ushort f2bf(float f) {
  unsigned int x = __float_as_uint(f);
  unsigned int r = (x + 0x7fffu + ((x >> 16) & 1u)) >> 16;
  return (ushort)r;
}

// async global->LDS, 16 B per lane. LDS dest is wave-uniform base + lane*16.
__device__ __forceinline__ void gload_lds16(const ushort* g, ushort* l) {
  __builtin_amdgcn_global_load_lds(
      (const __attribute__((address_space(1))) void*)g,
      (__attribute__((address_space(3))) void*)l, 16, 0, 0);
}

// ---------------------------------------------------------------------------
// Fused prep: convert x -> bf16 (blocks 0..4095), transpose+convert w_attn
// (blocks 4096..16383), transpose+convert w_proj (blocks 16384..20479).
// ---------------------------------------------------------------------------
#define CONVB 4096
#define WATB 12288  // (6144/32)*(2048/32)
#define WPTB 4096   // (2048/32)*(2048/32)
__global__ __launch_bounds__(256) void prep(const float* __restrict__ x,
                                            const float* __restrict__ wa,
                                            const float* __restrict__ wp,
                                            ushort* __restrict__ xb,
                                            ushort* __restrict__ wt_attn,
                                            ushort* __restrict__ wt_proj) {
  __shared__ ushort tile[32][33];
  int bid = blockIdx.x;
  if (bid < CONVB) {
    int i = bid * 2048 + threadIdx.x * 8;
    union { ushort u[8]; short8 v; } t;
#pragma unroll
    for (int j = 0; j < 8; j++) t.u[j] = f2bf(x[i + j]);
    *(short8*)(xb + i) = t.v;
    return;
  }
  const float* in;
  ushort* out;
  int N, bx, by;
  if (bid < CONVB + WATB) {
    int id = bid - CONVB;
    N = N3_; bx = id % 192; by = id / 192; in = wa; out = wt_attn;
  } else {
    int id = bid - (CONVB + WATB);
    N = D_; bx = id & 63; by = id >> 6; in = wp; out = wt_proj;
  }
  int n0 = bx * 32, k0 = by * 32;
  int tx = threadIdx.x & 31, ty = threadIdx.x >> 5;
#pragma unroll
  for (int i = ty; i < 32; i += 8)
    tile[i][tx] = f2bf(in[(size_t)(k0 + i) * N + n0 + tx]);
  __syncthreads();
#pragma unroll
  for (int i = ty; i < 32; i += 8)
    out[(size_t)(n0 + i) * 2048 + k0 + tx] = tile[tx][i];
}

// ===========================================================================
// 256x256 8-phase-style core (m201 port) for QKV.
// 8 waves 2Mx4N, per-wave 128x64 (1.33x better LDS-per-FLOP than 64x64).
// BK=32, 4-slot ring (128 KiB), 2 phases per K-tile of 16 MFMA each
// (B-frags register-reused across both phases). Per phase: {ds_read subtile;
// stage one quarter of tile t+3; BAR; lgkmcnt(0); setprio; 16 MFMA; setprio;
// BAR}. Counted vmcnt(8) once per K-tile (12 loads in flight -> retires
// exactly tile t+1's 4). T2 chunk-XOR swizzle both sides (r2/r3-verified
// 0-conflict): source chunk (tid&3)^((tid>>3)&3), read chunk
// quad^((l16>>1)&3).
// ===========================================================================
#define QBK 32
#define QNT (GKD / QBK)     // 64 K-tiles
#define QSLOT 16384         // ush: A[256][32] @0, B[256][32] @8192 (32 KiB)
#define QRING 4             // 128 KiB

struct QPtr { const ushort *a, *b; };

__device__ __forceinline__ void qstageA(const QPtr& gp, size_t kpos,
                                        ushort* slot, int w512) {
  gload_lds16(gp.a + kpos, slot + w512);
  gload_lds16(gp.a + kpos + (size_t)128 * GKD, slot + 4096 + w512);
}
__device__ __forceinline__ void qstageB(const QPtr& gp, size_t kpos,
                                        ushort* slot, int w512) {
  gload_lds16(gp.b + kpos, slot + 8192 + w512);
  gload_lds16(gp.b + kpos + (size_t)128 * GKD, slot + 12288 + w512);
}

// one K-tile = 2 phases
template <int VM, bool STG>
__device__ __forceinline__ void qtile(const QPtr& gp, size_t kpos,
                                      const ushort* rs, ushort* ss, int w512,
                                      const int (&aoff)[8], const int (&boff)[4],
                                      floatx4 (&acc)[8][4]) {
  // ---- phase 0: quadrant mi 0-3 x nj 0-3 ----
  short8 a0[4], bf[4];
#pragma unroll
  for (int i = 0; i < 4; i++) {
    a0[i] = *(const short8*)(rs + aoff[i]);
    bf[i] = *(const short8*)(rs + boff[i]);
  }
  if constexpr (STG) qstageA(gp, kpos, ss, w512);
  __builtin_amdgcn_sched_barrier(0);
  __builtin_amdgcn_s_barrier();
  asm volatile("s_waitcnt lgkmcnt(0)" ::: "memory");
  __builtin_amdgcn_sched_barrier(0);
  __builtin_amdgcn_s_setprio(1);
#pragma unroll
  for (int mi = 0; mi < 4; mi++)
#pragma unroll
    for (int nj = 0; nj < 4; nj++)
      acc[mi][nj] = __builtin_amdgcn_mfma_f32_16x16x32_bf16(
          a0[mi], bf[nj], acc[mi][nj], 0, 0, 0);
  __builtin_amdgcn_s_setprio(0);
  __builtin_amdgcn_sched_barrier(0);
  __builtin_amdgcn_s_barrier();
  __builtin_amdgcn_sched_barrier(0);
  // ---- phase 1: quadrant mi 4-7 x nj 0-3 (bf reused from regs) ----
  short8 a1[4];
#pragma unroll
  for (int i = 0; i < 4; i++) a1[i] = *(const short8*)(rs + aoff[4 + i]);
  if constexpr (STG) qstageB(gp, kpos, ss, w512);
  __builtin_amdgcn_sched_barrier(0);
  __builtin_amdgcn_s_barrier();
  asm volatile("s_waitcnt lgkmcnt(0)" ::: "memory");
  __builtin_amdgcn_sched_barrier(0);
  __builtin_amdgcn_s_setprio(1);
#pragma unroll
  for (int mi = 0; mi < 4; mi++)
#pragma unroll
    for (int nj = 0; nj < 4; nj++)
      acc[4 + mi][nj] = __builtin_amdgcn_mfma_f32_16x16x32_bf16(
          a1[mi], bf[nj], acc[4 + mi][nj], 0, 0, 0);
  __builtin_amdgcn_s_setprio(0);
  if constexpr (VM == 8) {
    asm volatile("s_waitcnt vmcnt(8)" ::: "memory");
  } else if constexpr (VM == 4) {
    asm volatile("s_waitcnt vmcnt(4)" ::: "memory");
  } else if constexpr (VM == 0) {
    asm volatile("s_waitcnt vmcnt(0)" ::: "memory");
  }
  __builtin_amdgcn_sched_barrier(0);
  __builtin_amdgcn_s_barrier();
  __builtin_amdgcn_sched_barrier(0);
}

__device__ __forceinline__ void qgemm_core(const ushort* __restrict__ Ag,
                                           const ushort* __restrict__ Bg,
                                           ushort* lds, floatx4 (&acc)[8][4]) {
  int tid = threadIdx.x;
  int lane = tid & 63, wave = tid >> 6;
  int l16 = lane & 15, quad = lane >> 4;
  int wr = wave >> 2, wcn = wave & 3;
  int w512 = wave * 512;

  // source-side swizzle: thread (row=tid>>2, chunk-slot=tid&3) loads global
  // chunk (tid&3) ^ ((row>>1)&3); +128-row load shares the same swizzle.
  int swz = ((tid & 3) ^ ((tid >> 3) & 3)) * 8;
  QPtr gp;
  gp.a = Ag + (size_t)(tid >> 2) * GKD + swz;
  gp.b = Bg + (size_t)(tid >> 2) * GKD + swz;

  // read-side swizzle chunk: quad ^ ((row>>1)&3) = quad ^ ((l16>>1)&3)
  int rchk8 = (quad ^ ((l16 >> 1) & 3)) * 8;
  int aoff[8], boff[4];
#pragma unroll
  for (int i = 0; i < 8; i++)
    aoff[i] = (wr * 128 + i * 16 + l16) * QBK + rchk8;
#pragma unroll
  for (int j = 0; j < 4; j++)
    boff[j] = 8192 + (wcn * 64 + j * 16 + l16) * QBK + rchk8;

  // prologue: stage tiles 0,1,2 (12 loads/thread)
#pragma unroll
  for (int t = 0; t < 3; t++) {
    ushort* s = lds + t * QSLOT;
    qstageA(gp, (size_t)t * QBK, s, w512);
    qstageB(gp, (size_t)t * QBK, s, w512);
  }
  asm volatile("s_waitcnt vmcnt(8)" ::: "memory");  // tile 0 landed
  __builtin_amdgcn_sched_barrier(0);
  __builtin_amdgcn_s_barrier();
  __builtin_amdgcn_sched_barrier(0);

  const ushort* rs = lds;
  ushort* ss = lds + 3 * QSLOT;
  ushort* const wrapp = lds + 3 * QSLOT;
#pragma unroll 1
  for (int t = 0; t < QNT - 3; ++t) {  // consume t, stage t+3
    qtile<8, true>(gp, (size_t)(t + 3) * QBK, rs, ss, w512, aoff, boff, acc);
    rs = (rs == wrapp) ? lds : rs + QSLOT;
    ss = (ss == wrapp) ? lds : ss + QSLOT;
  }
  // drains: t = 61 (vm->4: tile 62 lands), 62 (vm->0: tile 63), 63
  qtile<4, false>(gp, 0, rs, ss, w512, aoff, boff, acc);
  rs = (rs == wrapp) ? lds : rs + QSLOT;
  qtile<0, false>(gp, 0, rs, ss, w512, aoff, boff, acc);
  rs = (rs == wrapp) ? lds : rs + QSLOT;
  qtile<-1, false>(gp, 0, rs, ss, w512, aoff, boff, acc);
}

// ---------------------------------------------------------------------------
// QKV GEMM, 256x256 tile (2 heads wide). Q -> [B,H,T,HD].
// K -> staged image: per (b,h): [t>>6][d>>5][t&63][(d&31) ^ swz(t)],
//      swz(t) = ((t>>1)&3)<<3  (pre-swizzled for attn's ds_read, T2).
// V -> staged PV image: per (b,h): [t>>6][kc][d][(p&31) ^ swz(d)],
//      p=(c&15)*4+(c>>4), kc=p>>5, c=t&63, swz(d) = ((d>>1)&3)<<3.
// Grid: 384 blocks 1-D, bijective XCD swizzle (384 % 8 == 0), N-fastest.
// ---------------------------------------------------------------------------
__global__ __launch_bounds__(512, 2) void gemm_qkv(const ushort* __restrict__ X,
                                                   const ushort* __restrict__ Wt,
                                                   ushort* __restrict__ qb,
                                                   ushort* __restrict__ kb,
                                                   ushort* __restrict__ vst) {
  __shared__ __align__(16) ushort lds[QRING * QSLOT];  // 128 KiB
  floatx4 acc[8][4];
#pragma unroll
  for (int i = 0; i < 8; i++)
#pragma unroll
    for (int j = 0; j < 4; j++) acc[i][j] = (floatx4){0.f, 0.f, 0.f, 0.f};

  int bid = blockIdx.x;                       // 0..383
  int id = (bid & 7) * 48 + (bid >> 3);       // XCD-chunked, bijective
  int by = id / 24, bx = id % 24;
  int m0 = by * 256, n0 = bx * 256;
  qgemm_core(X + (size_t)m0 * GKD, Wt + (size_t)n0 * GKD, lds, acc);

  int tid = threadIdx.x, lane = tid & 63, wave = tid >> 6;
  int l16 = lane & 15, quad = lane >> 4, wr = wave >> 2, wcn = wave & 3;
  int region = n0 >> 11;  // 0=Q 1=K 2=V (256-tile never crosses a region)
  int h = ((n0 & 2047) >> 7) + (wcn >> 1);    // wave-uniform head
  int d0 = (wcn & 1) * 64;                    // within-head dim base
  int b = m0 >> 11, tb = m0 & 2047;
  if (region == 0) {
    ushort* P = qb + ((size_t)(b * H_ + h) * T_ + tb) * HD_;
#pragma unroll
    for (int mi = 0; mi < 8; mi++)
#pragma unroll
      for (int nj = 0; nj < 4; nj++)
#pragma unroll
        for (int r = 0; r < 4; r++)
          P[(size_t)(wr * 128 + mi * 16 + quad * 4 + r) * HD_ + d0 + nj * 16 +
            l16] = f2bf(acc[mi][nj][r]);
  } else if (region == 1) {
    ushort* base = kb + (size_t)(b * H_ + h) * T_ * HD_;
#pragma unroll
    for (int mi = 0; mi < 8; mi++)
#pragma unroll
      for (int nj = 0; nj < 4; nj++) {
        int d = d0 + nj * 16 + l16;
        int dhi = d >> 5, dlo = d & 31;
#pragma unroll
        for (int r = 0; r < 4; r++) {
          int t = tb + wr * 128 + mi * 16 + quad * 4 + r;
          int sK = ((quad * 4 + r) >> 1) & 3;  // = (t>>1)&3
          base[(size_t)(t >> 6) * 8192 + dhi * 2048 + (t & 63) * 32 +
               (dlo ^ (sK << 3))] = f2bf(acc[mi][nj][r]);
        }
      }
  } else {
    ushort* base = vst + (size_t)(b * H_ + h) * T_ * HD_;
    int sd = ((l16 >> 1) & 3) << 3;  // = ((d>>1)&3)<<3 for all nj
#pragma unroll
    for (int mi = 0; mi < 8; mi++)
#pragma unroll
      for (int r = 0; r < 4; r++) {
        int t = tb + wr * 128 + mi * 16 + quad * 4 + r;
        int c = t & 63;
        int p = (c & 15) * 4 + (c >> 4);
        size_t rowbase =
            (size_t)(t >> 6) * 8192 + (p >> 5) * 4096 + ((p & 31) ^ sd);
#pragma unroll
        for (int nj = 0; nj < 4; nj++) {
          int d = d0 + nj * 16 + l16;
          base[rowbase + d * 32] = f2bf(acc[mi][nj][r]);
        }
      }
  }
}

// ===========================================================================
// Proj core: r3-proven 256x128 / BK=64 / 3-ring pipelined core (exact grid:
// 256 blocks = 1 full round of 256 CUs).
// ===========================================================================
#define PBM 256
#define PBN 128
#define PBK 64
#define PNT (GKD / PBK)         // 32 K-steps
#define PA_US (PBM * PBK)       // 16384 ushorts
#define PB_US (PBN * PBK)       // 8192 ushorts
#define PBUF (PA_US + PB_US)    // 24576 ushorts (48 KiB)

struct PPtr { const ushort *a0, *b0; };

__device__ __forceinline__ void pstage(const PPtr& gp, size_t kpos,
                                       ushort* slot, int w512) {
#pragma unroll
  for (int j = 0; j < 4; j++)
    gload_lds16(gp.a0 + kpos + (size_t)j * 64 * GKD, slot + j * 4096 + w512);
#pragma unroll
  for (int j = 0; j < 2; j++)
    gload_lds16(gp.b0 + kpos + (size_t)j * 64 * GKD,
                slot + PA_US + j * 4096 + w512);
}

template <int VM, bool STG, bool BAR>
__device__ __forceinline__ void pstep(const PPtr& gp, size_t kpos,
                                      const ushort* Ac, const ushort* Bc,
                                      ushort* sslot, int w512,
                                      const int (&aoff)[4][2],
                                      const int (&boff)[4][2],
                                      floatx4 (&acc)[4][4]) {
  short8 af[4][2], bf[4][2];
#pragma unroll
  for (int kk = 0; kk < 2; kk++)
#pragma unroll
    for (int i = 0; i < 4; i++) {
      af[i][kk] = *(const short8*)(Ac + aoff[i][kk]);
      bf[i][kk] = *(const short8*)(Bc + boff[i][kk]);
    }
  if constexpr (STG) pstage(gp, kpos, sslot, w512);
  __builtin_amdgcn_s_setprio(1);
#pragma unroll
  for (int kk = 0; kk < 2; kk++)
#pragma unroll
    for (int mi = 0; mi < 4; mi++)
#pragma unroll
      for (int nj = 0; nj < 4; nj++)
        acc[mi][nj] = __builtin_amdgcn_mfma_f32_16x16x32_bf16(
            af[mi][kk], bf[nj][kk], acc[mi][nj], 0, 0, 0);
  __builtin_amdgcn_s_setprio(0);
  if constexpr (VM == 6) {
    asm volatile("s_waitcnt vmcnt(6)" ::: "memory");
  } else if constexpr (VM == 0) {
    asm volatile("s_waitcnt vmcnt(0)" ::: "memory");
  }
  if constexpr (BAR) {
    __builtin_amdgcn_sched_barrier(0);
    __builtin_amdgcn_s_barrier();
    __builtin_amdgcn_sched_barrier(0);
  }
}

__device__ __forceinline__ void pgemm_core(const ushort* __restrict__ Ag,
                                           const ushort* __restrict__ Bg,
                                           ushort* lds, floatx4 (&acc)[4][4]) {
  int tid = threadIdx.x;
  int lane = tid & 63, wave = tid >> 6;
  int l16 = lane & 15, quad = lane >> 4;
  int wr = wave >> 1, wc = wave & 1;
  int w512 = wave * 512;

  int swz = ((tid & 7) ^ ((tid >> 3) & 7)) * 8;
  PPtr gp;
  gp.a0 = Ag + (size_t)(tid >> 3) * GKD + swz;
  gp.b0 = Bg + (size_t)(tid >> 3) * GKD + swz;

  int aoff[4][2], boff[4][2];
#pragma unroll
  for (int i = 0; i < 4; i++)
#pragma unroll
    for (int kk = 0; kk < 2; kk++) {
      int chk = ((kk * 4 + quad) ^ (l16 & 7)) * 8;
      aoff[i][kk] = (wr * 64 + i * 16 + l16) * PBK + chk;
      boff[i][kk] = (wc * 64 + i * 16 + l16) * PBK + chk;
    }

  pstage(gp, 0, lds, w512);
  pstage(gp, PBK, lds + PBUF, w512);
  asm volatile("s_waitcnt vmcnt(6)" ::: "memory");
  __builtin_amdgcn_sched_barrier(0);
  __builtin_amdgcn_s_barrier();
  __builtin_amdgcn_sched_barrier(0);

  const ushort* cp = lds;
  ushort* sp = lds + 2 * PBUF;
#pragma unroll 1
  for (int t = 0; t < PNT - 2; ++t) {
    pstep<6, true, true>(gp, (size_t)(t + 2) * PBK, cp, cp + PA_US, sp, w512,
                         aoff, boff, acc);
    cp = (cp == lds + 2 * PBUF) ? lds : cp + PBUF;
    sp = (sp == lds + 2 * PBUF) ? lds : sp + PBUF;
  }
  pstep<0, false, true>(gp, 0, cp, cp + PA_US, lds, w512, aoff, boff, acc);
  cp = (cp == lds + 2 * PBUF) ? lds : cp + PBUF;
  pstep<-1, false, false>(gp, 0, cp, cp + PA_US, lds, w512, aoff, boff, acc);
}

// ---------------------------------------------------------------------------
// Proj GEMM: out fp32 [M,2048] = Y bf16 @ Wp (Wt = Wp^T bf16).
// ---------------------------------------------------------------------------
__global__ __launch_bounds__(512, 2) void gemm_proj(const ushort* __restrict__ Y,
                                                    const ushort* __restrict__ Wt,
                                                    float* __restrict__ out) {
  __shared__ __align__(16) ushort lds[3 * PBUF];  // 144 KiB
  floatx4 acc[4][4];
#pragma unroll
  for (int i = 0; i < 4; i++)
#pragma unroll
    for (int j = 0; j < 4; j++) acc[i][j] = (floatx4){0.f, 0.f, 0.f, 0.f};

  int m0 = blockIdx.y * PBM, n0 = blockIdx.x * PBN;
  pgemm_core(Y + (size_t)m0 * GKD, Wt + (size_t)n0 * GKD, lds, acc);

  int tid = threadIdx.x, lane = tid & 63, wave = tid >> 6;
  int l16 = lane & 15, quad = lane >> 4, wr = wave >> 1, wc = wave & 1;
#pragma unroll
  for (int mi = 0; mi < 4; mi++)
#pragma unroll
    for (int nj = 0; nj < 4; nj++)
#pragma unroll
      for (int r = 0; r < 4; r++)
        out[(size_t)(m0 + wr * 64 + mi * 16 + quad * 4 + r) * D_ + n0 +
            wc * 64 + nj * 16 + l16] = acc[mi][nj][r];
}

// ---------------------------------------------------------------------------
// Flash attention (causal), 4 waves / 128 queries per block, 64-key LDS
// tiles, double-buffered K/V. NO-MAX softmax. T2-swizzled K/V images.
// ---------------------------------------------------------------------------
__global__ __launch_bounds__(256) void attn128(const ushort* __restrict__ qb,
                                               const ushort* __restrict__ kst,
                                               const ushort* __restrict__ vst,
                                               ushort* __restrict__ y) {
  __shared__ ushort Ks[2][8192];  // [kk4][key64][k32 swizzled]
  __shared__ ushort Vs[2][8192];  // [kc2][d128][p32 swizzled]
  __shared__ ushort Ps[8192];     // 4 x per-wave 32x64 P tile (swizzled)
  int bid = blockIdx.x;
  int bh = bid & 31;
  int qt = (bid < 256) ? (bid >> 5) : (15 - ((bid - 256) >> 5));
  int q0 = qt * 128;
  int tid = threadIdx.x, lane = tid & 63, wave = tid >> 6;
  int l16 = lane & 15, quad = lane >> 4;
  int b = bh >> 4, h = bh & 15;
  const ushort* Q = qb + (size_t)bh * T_ * HD_;
  const ushort* Kt = kst + (size_t)bh * T_ * HD_;
  const ushort* Vt = vst + (size_t)bh * T_ * HD_;
  int qw0 = q0 + wave * 32;

  short8 qf[2][4];
#pragma unroll
  for (int mi = 0; mi < 2; mi++)
#pragma unroll
    for (int kk = 0; kk < 4; kk++)
      qf[mi][kk] = *(const short8*)(Q + (size_t)(qw0 + mi * 16 + l16) * HD_ +
                                    kk * 32 + quad * 8);

  floatx4 o[2][8];
#pragma unroll
  for (int mi = 0; mi < 2; mi++)
#pragma unroll
    for (int nt = 0; nt < 8; nt++) o[mi][nt] = (floatx4){0.f, 0.f, 0.f, 0.f};
  float lrow[2][4];  // per-lane partial of l (reduced after loop)
#pragma unroll
  for (int mi = 0; mi < 2; mi++)
#pragma unroll
    for (int r = 0; r < 4; r++) lrow[mi][r] = 0.f;

  // 1/sqrt(128) * log2(e): fold ln2 into the scale so p = exp2(s*scale2)
  const float scale2 = 0.08838834764831845f * 1.4426950408889634f;
  int ktiles = (q0 >> 6) + 2;
  // T2 read-side swizzle chunk for K/V fragment reads: quad ^ ((row>>1)&3)
  int vchk = (quad ^ ((l16 >> 1) & 3)) * 8;

  // prologue: stage tile 0 into buffer 0
#pragma unroll
  for (int i = 0; i < 4; i++) {
    int g = i * 256 + wave * 64;
    gload_lds16(Kt + (g + lane) * 8, Ks[0] + g * 8);
    gload_lds16(Vt + (g + lane) * 8, Vs[0] + g * 8);
  }
  __syncthreads();

  int cur = 0;
  for (int tile = 0; tile < ktiles; tile++) {
    int kt = tile << 6;
    if (tile + 1 < ktiles) {  // stage next tile into the other buffer
#pragma unroll
      for (int i = 0; i < 4; i++) {
        int g = i * 256 + wave * 64;
        gload_lds16(Kt + (size_t)(tile + 1) * 8192 + (g + lane) * 8,
                    Ks[cur ^ 1] + g * 8);
        gload_lds16(Vt + (size_t)(tile + 1) * 8192 + (g + lane) * 8,
                    Vs[cur ^ 1] + g * 8);
      }
    }
    if (kt <= qw0 + 31) {  // wave-uniform skip of fully-masked tiles
      const ushort* Ksb = Ks[cur];
      const ushort* Vsb = Vs[cur];
      floatx4 s[2][4];
#pragma unroll
      for (int mi = 0; mi < 2; mi++)
#pragma unroll
        for (int ng = 0; ng < 4; ng++) s[mi][ng] = (floatx4){0.f, 0.f, 0.f, 0.f};
#pragma unroll
      for (int kk = 0; kk < 4; kk++) {
        short8 kf[4];
#pragma unroll
        for (int ng = 0; ng < 4; ng++)
          kf[ng] = *(const short8*)(Ksb + kk * 2048 + (ng * 16 + l16) * 32 +
                                    vchk);
        __builtin_amdgcn_s_setprio(1);
#pragma unroll
        for (int mi = 0; mi < 2; mi++)
#pragma unroll
          for (int ng = 0; ng < 4; ng++)
            s[mi][ng] = __builtin_amdgcn_mfma_f32_16x16x32_bf16(
                qf[mi][kk], kf[ng], s[mi][ng], 0, 0, 0);
        __builtin_amdgcn_s_setprio(0);
      }
      // p = exp2(scale2 * s) with causal mask; accumulate per-lane l-partials
      if (kt + 63 > qw0) {
#pragma unroll
        for (int mi = 0; mi < 2; mi++)
#pragma unroll
          for (int ng = 0; ng < 4; ng++)
#pragma unroll
            for (int r = 0; r < 4; r++) {
              int key = kt + ng * 16 + l16;
              int qr = qw0 + mi * 16 + quad * 4 + r;
              float p =
                  (key <= qr) ? exp2f(s[mi][ng][r] * scale2) : 0.f;
              s[mi][ng][r] = p;
              lrow[mi][r] += p;
            }
      } else {
#pragma unroll
        for (int mi = 0; mi < 2; mi++)
#pragma unroll
          for (int ng = 0; ng < 4; ng++)
#pragma unroll
            for (int r = 0; r < 4; r++) {
              float p = exp2f(s[mi][ng][r] * scale2);
              s[mi][ng][r] = p;
              lrow[mi][r] += p;
            }
      }
      // P write: swizzled b64 packs (conflict-free); read as A-frag; PV MFMA
      ushort* Pw = Ps + wave * 2048;
#pragma unroll
      for (int mi = 0; mi < 2; mi++)
#pragma unroll
        for (int r = 0; r < 4; r++) {
          int row = mi * 16 + quad * 4 + r;
          short4v pk;
#pragma unroll
          for (int ng = 0; ng < 4; ng++) pk[ng] = (short)f2bf(s[mi][ng][r]);
          *(short4v*)(Pw + row * 64 + (((l16 >> 1) ^ (row & 7)) << 3) +
                      ((l16 & 1) << 2)) = pk;
        }
      short8 pf[2][2];
#pragma unroll
      for (int mi = 0; mi < 2; mi++)
#pragma unroll
        for (int kc = 0; kc < 2; kc++) {
          int row = mi * 16 + l16;
          pf[mi][kc] = *(const short8*)(
              Pw + row * 64 + ((((kc << 2) + quad) ^ (row & 7)) << 3));
        }
#pragma unroll
      for (int kc = 0; kc < 2; kc++) {
#pragma unroll
        for (int nt = 0; nt < 8; nt++) {
          short8 vf = *(const short8*)(Vsb + kc * 4096 + (nt * 16 + l16) * 32 +
                                       vchk);
          __builtin_amdgcn_s_setprio(1);
#pragma unroll
          for (int mi = 0; mi < 2; mi++)
            o[mi][nt] = __builtin_amdgcn_mfma_f32_16x16x32_bf16(
                pf[mi][kc], vf, o[mi][nt], 0, 0, 0);
          __builtin_amdgcn_s_setprio(0);
        }
      }
    }
    __syncthreads();  // drains vmcnt/lgkmcnt: next tile staged + buffers free
    cur ^= 1;
  }

  // deferred l reduction (single 4-step shuffle chain per row)
#pragma unroll
  for (int off = 1; off < 16; off <<= 1)
#pragma unroll
    for (int mi = 0; mi < 2; mi++)
#pragma unroll
      for (int r = 0; r < 4; r++)
        lrow[mi][r] += __shfl_xor(lrow[mi][r], off);

#pragma unroll
  for (int mi = 0; mi < 2; mi++)
#pragma unroll
    for (int r = 0; r < 4; r++) {
      float inv = 1.f / lrow[mi][r];
      int t = qw0 + mi * 16 + quad * 4 + r;
#pragma unroll
      for (int nt = 0; nt < 8; nt++)
        y[((size_t)(b * T_ + t)) * D_ + h * HD_ + nt * 16 + l16] =
            f2bf(o[mi][nt][r] * inv);
    }
}

// ---------------------------------------------------------------------------
extern "C" void kernel_launch(void* const* d_in, const int* in_sizes, int n_in,
                              void* d_out, int out_size, void* d_ws,
                              size_t ws_size, hipStream_t stream) {
  const float* x = (const float*)d_in[0];       // [B,T,D]  fp32
  const float* w_attn = (const float*)d_in[1];  // [D,3D]   fp32
  const float* w_proj = (const float*)d_in[2];  // [D,D]    fp32
  float* out = (float*)d_out;                   // [B,T,D]  fp32

  // Workspace (100.66 MB). yb aliases xb (dead after gemm_qkv).
  char* ws = (char*)d_ws;
  ushort* wt_attn = (ushort*)(ws);             // [6144][2048]  25.2 MB
  ushort* wt_proj = (ushort*)(ws + 25165824);  // [2048][2048]   8.4 MB
  ushort* qb = (ushort*)(ws + 33554432);       // [B,H,T,HD]    16.8 MB
  ushort* kb = (ushort*)(ws + 50331648);       // K staged      16.8 MB
  ushort* vst = (ushort*)(ws + 67108864);      // V staged      16.8 MB
  ushort* xb = (ushort*)(ws + 83886080);       // [M][D]        16.8 MB
  ushort* yb = xb;                             // alias
  (void)in_sizes; (void)n_in; (void)out_size; (void)ws_size;

  prep<<<CONVB + WATB + WPTB, 256, 0, stream>>>(x, w_attn, w_proj, xb,
                                                wt_attn, wt_proj);
  gemm_qkv<<<(N3_ / 256) * (M_ / 256), 512, 0, stream>>>(xb, wt_attn, qb, kb,
                                                         vst);
  attn128<<<B_ * H_ * (T_ / 128), 256, 0, stream>>>(qb, kb, vst, yb);
  gemm_proj<<<dim3(D_ / PBN, M_ / PBM), 512, 0, stream>>>(yb, wt_proj, out);
}

// Round 7
// 376.414 us; speedup vs baseline: 1.0573x; 1.0573x over previous
//
#include <hip/hip_runtime.h>
#include <hip/hip_bf16.h>

// Problem: B=2, T=2048, D=2048, H=16, HD=128.
// Inputs fp32, output fp32. Compute via bf16 MFMA, fp32 acc.
#define B_ 2
#define T_ 2048
#define D_ 2048
#define H_ 16
#define HD_ 128
#define N3_ (3 * D_)
#define M_ (B_ * T_)
#define GKD 2048

typedef __attribute__((ext_vector_type(8))) short short8;   // 8 x bf16
typedef __attribute__((ext_vector_type(4))) short short4v;  // 4 x bf16 (8 B)
typedef __attribute__((ext_vector_type(4))) float floatx4;  // 4 x fp32 acc

// round-to-nearest-even f32 -> bf16 bits
__device__ __forceinline__ ushort f2bf(float f) {
  unsigned int x = __float_as_uint(f);
  unsigned int r = (x + 0x7fffu + ((x >> 16) & 1u)) >> 16;
  return (ushort)r;
}

// async global->LDS, 16 B per lane. LDS dest is wave-uniform base + lane*16.
__device__ __forceinline__ void gload_lds16(const ushort* g, ushort* l) {
  __builtin_amdgcn_global_load_lds(
      (const __attribute__((address_space(1))) void*)g,
      (__attribute__((address_space(3))) void*)l, 16, 0, 0);
}

// ---------------------------------------------------------------------------
// Fused prep: convert x -> bf16 (blocks 0..4095), transpose+convert w_attn
// (blocks 4096..16383), transpose+convert w_proj (blocks 16384..20479).
// ---------------------------------------------------------------------------
#define CONVB 4096
#define WATB 12288  // (6144/32)*(2048/32)
#define WPTB 4096   // (2048/32)*(2048/32)
__global__ __launch_bounds__(256) void prep(const float* __restrict__ x,
                                            const float* __restrict__ wa,
                                            const float* __restrict__ wp,
                                            ushort* __restrict__ xb,
                                            ushort* __restrict__ wt_attn,
                                            ushort* __restrict__ wt_proj) {
  __shared__ ushort tile[32][33];
  int bid = blockIdx.x;
  if (bid < CONVB) {
    int i = bid * 2048 + threadIdx.x * 8;
    union { ushort u[8]; short8 v; } t;
#pragma unroll
    for (int j = 0; j < 8; j++) t.u[j] = f2bf(x[i + j]);
    *(short8*)(xb + i) = t.v;
    return;
  }
  const float* in;
  ushort* out;
  int N, bx, by;
  if (bid < CONVB + WATB) {
    int id = bid - CONVB;
    N = N3_; bx = id % 192; by = id / 192; in = wa; out = wt_attn;
  } else {
    int id = bid - (CONVB + WATB);
    N = D_; bx = id & 63; by = id >> 6; in = wp; out = wt_proj;
  }
  int n0 = bx * 32, k0 = by * 32;
  int tx = threadIdx.x & 31, ty = threadIdx.x >> 5;
#pragma unroll
  for (int i = ty; i < 32; i += 8)
    tile[i][tx] = f2bf(in[(size_t)(k0 + i) * N + n0 + tx]);
  __syncthreads();
#pragma unroll
  for (int i = ty; i < 32; i += 8)
    out[(size_t)(n0 + i) * 2048 + k0 + tx] = tile[tx][i];
}

// ===========================================================================
// QKV core: 256x128 tile, 8 waves 4Mx2N (per-wave 64x64), BK=32, ring-3
// (72 KiB LDS -> 2 blocks/CU, 4 waves/SIMD: cross-block TLP covers the
// LDS-read and barrier windows that serialized the 1-block/CU variants).
// One s_barrier per K-step; stage distance 2; counted vmcnt(3) (3 loads/tile,
// 6 in flight after stage -> retires next tile exactly); setprio on MFMA.
// T2 chunk-XOR swizzle both sides (r2/r3-verified 0-conflict): source chunk
// (tid&3)^((tid>>3)&3), read chunk quad^((l16>>1)&3).
// ===========================================================================
#define GBM 256
#define GBN 128
#define GBK 32
#define GNT (GKD / GBK)        // 64 K-tiles
#define A_US (GBM * GBK)       // 8192 ushorts (16 KiB)
#define B_US (GBN * GBK)       // 4096 ushorts (8 KiB)
#define BUF_US (A_US + B_US)   // 12288 ushorts (24 KiB)
#define RING 3                 // 72 KiB

struct QPtr {
  const ushort* a0;  // A rows 0..127   (this thread's swizzled chunk)
  const ushort* a1;  // A rows 128..255
  const ushort* b0;  // B rows 0..127
};

template <int VM, bool STG, bool BAR>
__device__ __forceinline__ void kstep(const QPtr& gp, size_t kpos,
                                      const ushort* cs, ushort* ss, int w512,
                                      const int (&arow)[4], const int (&brow)[4],
                                      floatx4 (&acc)[4][4]) {
  short8 af[4], bf[4];
#pragma unroll
  for (int i = 0; i < 4; i++) {
    af[i] = *(const short8*)(cs + arow[i]);
    bf[i] = *(const short8*)(cs + A_US + brow[i]);
  }
  if constexpr (STG) {
    gload_lds16(gp.a0 + kpos, ss + w512);
    gload_lds16(gp.a1 + kpos, ss + 4096 + w512);
    gload_lds16(gp.b0 + kpos, ss + A_US + w512);
  }
  __builtin_amdgcn_s_setprio(1);
#pragma unroll
  for (int mi = 0; mi < 4; mi++)
#pragma unroll
    for (int nj = 0; nj < 4; nj++)
      acc[mi][nj] = __builtin_amdgcn_mfma_f32_16x16x32_bf16(
          af[mi], bf[nj], acc[mi][nj], 0, 0, 0);
  __builtin_amdgcn_s_setprio(0);
  if constexpr (VM == 3) {
    asm volatile("s_waitcnt vmcnt(3)" ::: "memory");
  } else if constexpr (VM == 0) {
    asm volatile("s_waitcnt vmcnt(0)" ::: "memory");
  }
  if constexpr (BAR) {
    __builtin_amdgcn_sched_barrier(0);
    __builtin_amdgcn_s_barrier();
    __builtin_amdgcn_sched_barrier(0);
  }
}

__device__ __forceinline__ void qgemm_core(const ushort* __restrict__ Ag,
                                           const ushort* __restrict__ Bg,
                                           ushort* lds, floatx4 (&acc)[4][4]) {
  int tid = threadIdx.x;
  int lane = tid & 63, wave = tid >> 6;
  int l16 = lane & 15, quad = lane >> 4;
  int wr = wave >> 1, wc = wave & 1;
  int w512 = wave * 512;

  // source-side swizzle: thread (row=tid>>2, chunk-slot=tid&3) loads global
  // chunk (tid&3) ^ ((row>>1)&3).
  int swz = ((tid & 3) ^ ((tid >> 3) & 3)) * 8;
  QPtr gp;
  gp.a0 = Ag + (size_t)(tid >> 2) * GKD + swz;
  gp.a1 = gp.a0 + (size_t)128 * GKD;
  gp.b0 = Bg + (size_t)(tid >> 2) * GKD + swz;

  // read-side swizzle: chunk = quad ^ ((row>>1)&3), (row>>1)&3 = (l16>>1)&3.
  int rchk = (quad ^ ((l16 >> 1) & 3)) * 8;
  int arow[4], brow[4];
#pragma unroll
  for (int i = 0; i < 4; i++) {
    arow[i] = (wr * 64 + i * 16 + l16) * GBK + rchk;
    brow[i] = (wc * 64 + i * 16 + l16) * GBK + rchk;
  }

  // prologue: stage K-tiles 0,1 into ring slots 0,1 (6 loads/thread)
#pragma unroll
  for (int t = 0; t < 2; t++) {
    ushort* s = lds + t * BUF_US;
    gload_lds16(gp.a0 + (size_t)t * GBK, s + w512);
    gload_lds16(gp.a1 + (size_t)t * GBK, s + 4096 + w512);
    gload_lds16(gp.b0 + (size_t)t * GBK, s + A_US + w512);
  }
  asm volatile("s_waitcnt vmcnt(3)" ::: "memory");  // tile 0 landed
  __builtin_amdgcn_sched_barrier(0);
  __builtin_amdgcn_s_barrier();
  __builtin_amdgcn_sched_barrier(0);

  const ushort* cs = lds;
  ushort* ss = lds + 2 * BUF_US;
  ushort* const wrapp = lds + 2 * BUF_US;
#pragma unroll 1
  for (int t = 0; t < GNT - 2; ++t) {  // consume t, stage t+2
    kstep<3, true, true>(gp, (size_t)(t + 2) * GBK, cs, ss, w512, arow, brow,
                         acc);
    cs = (cs == wrapp) ? lds : cs + BUF_US;
    ss = (ss == wrapp) ? lds : ss + BUF_US;
  }
  // t = GNT-2: no stage; drain last tile's loads
  kstep<0, false, true>(gp, 0, cs, ss, w512, arow, brow, acc);
  cs = (cs == wrapp) ? lds : cs + BUF_US;
  // t = GNT-1: nothing outstanding
  kstep<-1, false, false>(gp, 0, cs, ss, w512, arow, brow, acc);
}

// ---------------------------------------------------------------------------
// QKV GEMM. BN=128=HD: block-uniform epilogue. Q -> [B,H,T,HD].
// K -> staged image: per (b,h): [t>>6][d>>5][t&63][(d&31) ^ swz(t)],
//      swz(t) = ((t>>1)&3)<<3  (pre-swizzled for attn's ds_read, T2).
// V -> staged PV image: per (b,h): [t>>6][kc][d][(p&31) ^ swz(d)],
//      p=(c&15)*4+(c>>4), kc=p>>5, c=t&63, swz(d) = ((d>>1)&3)<<3.
// ---------------------------------------------------------------------------
__global__ __launch_bounds__(512, 4) void gemm_qkv(const ushort* __restrict__ X,
                                                   const ushort* __restrict__ Wt,
                                                   ushort* __restrict__ qb,
                                                   ushort* __restrict__ kb,
                                                   ushort* __restrict__ vst) {
  __shared__ __align__(16) ushort lds[RING * BUF_US];  // 72 KiB -> 2 blk/CU
  floatx4 acc[4][4];
#pragma unroll
  for (int i = 0; i < 4; i++)
#pragma unroll
    for (int j = 0; j < 4; j++) acc[i][j] = (floatx4){0.f, 0.f, 0.f, 0.f};

  int m0 = blockIdx.y * GBM, n0 = blockIdx.x * GBN;
  qgemm_core(X + (size_t)m0 * GKD, Wt + (size_t)n0 * GKD, lds, acc);

  int tid = threadIdx.x, lane = tid & 63, wave = tid >> 6;
  int l16 = lane & 15, quad = lane >> 4, wr = wave >> 1, wc = wave & 1;
  int region = n0 >> 11;  // 0=Q 1=K 2=V
  int h = (n0 & 2047) >> 7;
  int b = m0 >> 11, tb = m0 & 2047;
  if (region == 0) {
    ushort* P = qb + ((size_t)(b * H_ + h) * T_ + tb) * HD_;
#pragma unroll
    for (int mi = 0; mi < 4; mi++)
#pragma unroll
      for (int nj = 0; nj < 4; nj++)
#pragma unroll
        for (int r = 0; r < 4; r++)
          P[(size_t)(wr * 64 + mi * 16 + quad * 4 + r) * HD_ + wc * 64 +
            nj * 16 + l16] = f2bf(acc[mi][nj][r]);
  } else if (region == 1) {
    ushort* base = kb + (size_t)(b * H_ + h) * T_ * HD_;
#pragma unroll
    for (int mi = 0; mi < 4; mi++)
#pragma unroll
      for (int nj = 0; nj < 4; nj++) {
        int d = wc * 64 + nj * 16 + l16;
        int dhi = d >> 5, dlo = d & 31;
#pragma unroll
        for (int r = 0; r < 4; r++) {
          int t = tb + wr * 64 + mi * 16 + quad * 4 + r;
          int sK = ((quad * 4 + r) >> 1) & 3;  // = (t>>1)&3
          base[(size_t)(t >> 6) * 8192 + dhi * 2048 + (t & 63) * 32 +
               (dlo ^ (sK << 3))] = f2bf(acc[mi][nj][r]);
        }
      }
  } else {
    ushort* base = vst + (size_t)(b * H_ + h) * T_ * HD_;
    int sd = ((l16 >> 1) & 3) << 3;  // = ((d>>1)&3)<<3 for all nj
#pragma unroll
    for (int mi = 0; mi < 4; mi++)
#pragma unroll
      for (int r = 0; r < 4; r++) {
        int t = tb + wr * 64 + mi * 16 + quad * 4 + r;
        int c = t & 63;
        int p = (c & 15) * 4 + (c >> 4);
        size_t rowbase =
            (size_t)(t >> 6) * 8192 + (p >> 5) * 4096 + ((p & 31) ^ sd);
#pragma unroll
        for (int nj = 0; nj < 4; nj++) {
          int d = wc * 64 + nj * 16 + l16;
          base[rowbase + d * 32] = f2bf(acc[mi][nj][r]);
        }
      }
  }
}

// ===========================================================================
// Proj core: r3-proven 256x128 / BK=64 / 3-ring pipelined core (exact grid:
// 256 blocks = 1 full round of 256 CUs).
// ===========================================================================
#define PBM 256
#define PBN 128
#define PBK 64
#define PNT (GKD / PBK)         // 32 K-steps
#define PA_US (PBM * PBK)       // 16384 ushorts
#define PB_US (PBN * PBK)       // 8192 ushorts
#define PBUF (PA_US + PB_US)    // 24576 ushorts (48 KiB)

struct PPtr { const ushort *a0, *b0; };

__device__ __forceinline__ void pstage(const PPtr& gp, size_t kpos,
                                       ushort* slot, int w512) {
#pragma unroll
  for (int j = 0; j < 4; j++)
    gload_lds16(gp.a0 + kpos + (size_t)j * 64 * GKD, slot + j * 4096 + w512);
#pragma unroll
  for (int j = 0; j < 2; j++)
    gload_lds16(gp.b0 + kpos + (size_t)j * 64 * GKD,
                slot + PA_US + j * 4096 + w512);
}

template <int VM, bool STG, bool BAR>
__device__ __forceinline__ void pstep(const PPtr& gp, size_t kpos,
                                      const ushort* Ac, const ushort* Bc,
                                      ushort* sslot, int w512,
                                      const int (&aoff)[4][2],
                                      const int (&boff)[4][2],
                                      floatx4 (&acc)[4][4]) {
  short8 af[4][2], bf[4][2];
#pragma unroll
  for (int kk = 0; kk < 2; kk++)
#pragma unroll
    for (int i = 0; i < 4; i++) {
      af[i][kk] = *(const short8*)(Ac + aoff[i][kk]);
      bf[i][kk] = *(const short8*)(Bc + boff[i][kk]);
    }
  if constexpr (STG) pstage(gp, kpos, sslot, w512);
  __builtin_amdgcn_s_setprio(1);
#pragma unroll
  for (int kk = 0; kk < 2; kk++)
#pragma unroll
    for (int mi = 0; mi < 4; mi++)
#pragma unroll
      for (int nj = 0; nj < 4; nj++)
        acc[mi][nj] = __builtin_amdgcn_mfma_f32_16x16x32_bf16(
            af[mi][kk], bf[nj][kk], acc[mi][nj], 0, 0, 0);
  __builtin_amdgcn_s_setprio(0);
  if constexpr (VM == 6) {
    asm volatile("s_waitcnt vmcnt(6)" ::: "memory");
  } else if constexpr (VM == 0) {
    asm volatile("s_waitcnt vmcnt(0)" ::: "memory");
  }
  if constexpr (BAR) {
    __builtin_amdgcn_sched_barrier(0);
    __builtin_amdgcn_s_barrier();
    __builtin_amdgcn_sched_barrier(0);
  }
}

__device__ __forceinline__ void pgemm_core(const ushort* __restrict__ Ag,
                                           const ushort* __restrict__ Bg,
                                           ushort* lds, floatx4 (&acc)[4][4]) {
  int tid = threadIdx.x;
  int lane = tid & 63, wave = tid >> 6;
  int l16 = lane & 15, quad = lane >> 4;
  int wr = wave >> 1, wc = wave & 1;
  int w512 = wave * 512;

  int swz = ((tid & 7) ^ ((tid >> 3) & 7)) * 8;
  PPtr gp;
  gp.a0 = Ag + (size_t)(tid >> 3) * GKD + swz;
  gp.b0 = Bg + (size_t)(tid >> 3) * GKD + swz;

  int aoff[4][2], boff[4][2];
#pragma unroll
  for (int i = 0; i < 4; i++)
#pragma unroll
    for (int kk = 0; kk < 2; kk++) {
      int chk = ((kk * 4 + quad) ^ (l16 & 7)) * 8;
      aoff[i][kk] = (wr * 64 + i * 16 + l16) * PBK + chk;
      boff[i][kk] = (wc * 64 + i * 16 + l16) * PBK + chk;
    }

  pstage(gp, 0, lds, w512);
  pstage(gp, PBK, lds + PBUF, w512);
  asm volatile("s_waitcnt vmcnt(6)" ::: "memory");
  __builtin_amdgcn_sched_barrier(0);
  __builtin_amdgcn_s_barrier();
  __builtin_amdgcn_sched_barrier(0);

  const ushort* cp = lds;
  ushort* sp = lds + 2 * PBUF;
#pragma unroll 1
  for (int t = 0; t < PNT - 2; ++t) {
    pstep<6, true, true>(gp, (size_t)(t + 2) * PBK, cp, cp + PA_US, sp, w512,
                         aoff, boff, acc);
    cp = (cp == lds + 2 * PBUF) ? lds : cp + PBUF;
    sp = (sp == lds + 2 * PBUF) ? lds : sp + PBUF;
  }
  pstep<0, false, true>(gp, 0, cp, cp + PA_US, lds, w512, aoff, boff, acc);
  cp = (cp == lds + 2 * PBUF) ? lds : cp + PBUF;
  pstep<-1, false, false>(gp, 0, cp, cp + PA_US, lds, w512, aoff, boff, acc);
}

// ---------------------------------------------------------------------------
// Proj GEMM: out fp32 [M,2048] = Y bf16 @ Wp (Wt = Wp^T bf16).
// ---------------------------------------------------------------------------
__global__ __launch_bounds__(512, 2) void gemm_proj(const ushort* __restrict__ Y,
                                                    const ushort* __restrict__ Wt,
                                                    float* __restrict__ out) {
  __shared__ __align__(16) ushort lds[3 * PBUF];  // 144 KiB
  floatx4 acc[4][4];
#pragma unroll
  for (int i = 0; i < 4; i++)
#pragma unroll
    for (int j = 0; j < 4; j++) acc[i][j] = (floatx4){0.f, 0.f, 0.f, 0.f};

  int m0 = blockIdx.y * PBM, n0 = blockIdx.x * PBN;
  pgemm_core(Y + (size_t)m0 * GKD, Wt + (size_t)n0 * GKD, lds, acc);

  int tid = threadIdx.x, lane = tid & 63, wave = tid >> 6;
  int l16 = lane & 15, quad = lane >> 4, wr = wave >> 1, wc = wave & 1;
#pragma unroll
  for (int mi = 0; mi < 4; mi++)
#pragma unroll
    for (int nj = 0; nj < 4; nj++)
#pragma unroll
      for (int r = 0; r < 4; r++)
        out[(size_t)(m0 + wr * 64 + mi * 16 + quad * 4 + r) * D_ + n0 +
            wc * 64 + nj * 16 + l16] = acc[mi][nj][r];
}

// ---------------------------------------------------------------------------
// Flash attention (causal), 4 waves / 128 queries per block, 64-key LDS
// tiles, SINGLE-buffered (measured best: 40 KiB LDS -> higher occupancy
// beats dbuf overlap). NO-MAX softmax. T2-swizzled K/V staged images.
// ---------------------------------------------------------------------------
__global__ __launch_bounds__(256) void attn128(const ushort* __restrict__ qb,
                                               const ushort* __restrict__ kst,
                                               const ushort* __restrict__ vst,
                                               ushort* __restrict__ y) {
  __shared__ ushort Ks[8192];  // [kk4][key64][k32 swizzled]
  __shared__ ushort Vs[8192];  // [kc2][d128][p32 swizzled]
  __shared__ ushort Ps[8192];  // 4 x per-wave 32x64 P tile (swizzled)
  int bid = blockIdx.x;
  int bh = bid & 31;
  int qt = (bid < 256) ? (bid >> 5) : (15 - ((bid - 256) >> 5));
  int q0 = qt * 128;
  int tid = threadIdx.x, lane = tid & 63, wave = tid >> 6;
  int l16 = lane & 15, quad = lane >> 4;
  int b = bh >> 4, h = bh & 15;
  const ushort* Q = qb + (size_t)bh * T_ * HD_;
  const ushort* Kt = kst + (size_t)bh * T_ * HD_;
  const ushort* Vt = vst + (size_t)bh * T_ * HD_;
  int qw0 = q0 + wave * 32;

  short8 qf[2][4];
#pragma unroll
  for (int mi = 0; mi < 2; mi++)
#pragma unroll
    for (int kk = 0; kk < 4; kk++)
      qf[mi][kk] = *(const short8*)(Q + (size_t)(qw0 + mi * 16 + l16) * HD_ +
                                    kk * 32 + quad * 8);

  floatx4 o[2][8];
#pragma unroll
  for (int mi = 0; mi < 2; mi++)
#pragma unroll
    for (int nt = 0; nt < 8; nt++) o[mi][nt] = (floatx4){0.f, 0.f, 0.f, 0.f};
  float lrow[2][4];  // per-lane partial of l (reduced after loop)
#pragma unroll
  for (int mi = 0; mi < 2; mi++)
#pragma unroll
    for (int r = 0; r < 4; r++) lrow[mi][r] = 0.f;

  // 1/sqrt(128) * log2(e): fold ln2 into the scale so p = exp2(s*scale2)
  const float scale2 = 0.08838834764831845f * 1.4426950408889634f;
  int ktiles = (q0 >> 6) + 2;
  // T2 read-side swizzle chunk for K/V fragment reads: quad ^ ((row>>1)&3)
  int vchk = (quad ^ ((l16 >> 1) & 3)) * 8;

  for (int tile = 0; tile < ktiles; tile++) {
    int kt = tile << 6;
    __syncthreads();
#pragma unroll
    for (int i = 0; i < 4; i++) {
      int g = i * 256 + wave * 64;
      gload_lds16(Kt + (size_t)tile * 8192 + (g + lane) * 8, Ks + g * 8);
      gload_lds16(Vt + (size_t)tile * 8192 + (g + lane) * 8, Vs + g * 8);
    }
    __syncthreads();
    if (kt <= qw0 + 31) {  // wave-uniform skip of fully-masked tiles
      floatx4 s[2][4];
#pragma unroll
      for (int mi = 0; mi < 2; mi++)
#pragma unroll
        for (int ng = 0; ng < 4; ng++) s[mi][ng] = (floatx4){0.f, 0.f, 0.f, 0.f};
#pragma unroll
      for (int kk = 0; kk < 4; kk++) {
        short8 kf[4];
#pragma unroll
        for (int ng = 0; ng < 4; ng++)
          kf[ng] = *(const short8*)(Ks + kk * 2048 + (ng * 16 + l16) * 32 +
                                    vchk);
        __builtin_amdgcn_s_setprio(1);
#pragma unroll
        for (int mi = 0; mi < 2; mi++)
#pragma unroll
          for (int ng = 0; ng < 4; ng++)
            s[mi][ng] = __builtin_amdgcn_mfma_f32_16x16x32_bf16(
                qf[mi][kk], kf[ng], s[mi][ng], 0, 0, 0);
        __builtin_amdgcn_s_setprio(0);
      }
      // p = exp2(scale2 * s) with causal mask; accumulate per-lane l-partials
      if (kt + 63 > qw0) {
#pragma unroll
        for (int mi = 0; mi < 2; mi++)
#pragma unroll
          for (int ng = 0; ng < 4; ng++)
#pragma unroll
            for (int r = 0; r < 4; r++) {
              int key = kt + ng * 16 + l16;
              int qr = qw0 + mi * 16 + quad * 4 + r;
              float p =
                  (key <= qr) ? exp2f(s[mi][ng][r] * scale2) : 0.f;
              s[mi][ng][r] = p;
              lrow[mi][r] += p;
            }
      } else {
#pragma unroll
        for (int mi = 0; mi < 2; mi++)
#pragma unroll
          for (int ng = 0; ng < 4; ng++)
#pragma unroll
            for (int r = 0; r < 4; r++) {
              float p = exp2f(s[mi][ng][r] * scale2);
              s[mi][ng][r] = p;
              lrow[mi][r] += p;
            }
      }
      // P write: swizzled b64 packs (conflict-free); read as A-frag; PV MFMA
      ushort* Pw = Ps + wave * 2048;
#pragma unroll
      for (int mi = 0; mi < 2; mi++)
#pragma unroll
        for (int r = 0; r < 4; r++) {
          int row = mi * 16 + quad * 4 + r;
          short4v pk;
#pragma unroll
          for (int ng = 0; ng < 4; ng++) pk[ng] = (short)f2bf(s[mi][ng][r]);
          *(short4v*)(Pw + row * 64 + (((l16 >> 1) ^ (row & 7)) << 3) +
                      ((l16 & 1) << 2)) = pk;
        }
      short8 pf[2][2];
#pragma unroll
      for (int mi = 0; mi < 2; mi++)
#pragma unroll
        for (int kc = 0; kc < 2; kc++) {
          int row = mi * 16 + l16;
          pf[mi][kc] = *(const short8*)(
              Pw + row * 64 + ((((kc << 2) + quad) ^ (row & 7)) << 3));
        }
#pragma unroll
      for (int kc = 0; kc < 2; kc++) {
#pragma unroll
        for (int nt = 0; nt < 8; nt++) {
          short8 vf = *(const short8*)(Vs + kc * 4096 + (nt * 16 + l16) * 32 +
                                       vchk);
          __builtin_amdgcn_s_setprio(1);
#pragma unroll
          for (int mi = 0; mi < 2; mi++)
            o[mi][nt] = __builtin_amdgcn_mfma_f32_16x16x32_bf16(
                pf[mi][kc], vf, o[mi][nt], 0, 0, 0);
          __builtin_amdgcn_s_setprio(0);
        }
      }
    }
  }

  // deferred l reduction (single 4-step shuffle chain per row)
#pragma unroll
  for (int off = 1; off < 16; off <<= 1)
#pragma unroll
    for (int mi = 0; mi < 2; mi++)
#pragma unroll
      for (int r = 0; r < 4; r++)
        lrow[mi][r] += __shfl_xor(lrow[mi][r], off);

#pragma unroll
  for (int mi = 0; mi < 2; mi++)
#pragma unroll
    for (int r = 0; r < 4; r++) {
      float inv = 1.f / lrow[mi][r];
      int t = qw0 + mi * 16 + quad * 4 + r;
#pragma unroll
      for (int nt = 0; nt < 8; nt++)
        y[((size_t)(b * T_ + t)) * D_ + h * HD_ + nt * 16 + l16] =
            f2bf(o[mi][nt][r] * inv);
    }
}

// ---------------------------------------------------------------------------
extern "C" void kernel_launch(void* const* d_in, const int* in_sizes, int n_in,
                              void* d_out, int out_size, void* d_ws,
                              size_t ws_size, hipStream_t stream) {
  const float* x = (const float*)d_in[0];       // [B,T,D]  fp32
  const float* w_attn = (const float*)d_in[1];  // [D,3D]   fp32
  const float* w_proj = (const float*)d_in[2];  // [D,D]    fp32
  float* out = (float*)d_out;                   // [B,T,D]  fp32

  // Workspace (100.66 MB). yb aliases xb (dead after gemm_qkv).
  char* ws = (char*)d_ws;
  ushort* wt_attn = (ushort*)(ws);             // [6144][2048]  25.2 MB
  ushort* wt_proj = (ushort*)(ws + 25165824);  // [2048][2048]   8.4 MB
  ushort* qb = (ushort*)(ws + 33554432);       // [B,H,T,HD]    16.8 MB
  ushort* kb = (ushort*)(ws + 50331648);       // K staged      16.8 MB
  ushort* vst = (ushort*)(ws + 67108864);      // V staged      16.8 MB
  ushort* xb = (ushort*)(ws + 83886080);       // [M][D]        16.8 MB
  ushort* yb = xb;                             // alias
  (void)in_sizes; (void)n_in; (void)out_size; (void)ws_size;

  prep<<<CONVB + WATB + WPTB, 256, 0, stream>>>(x, w_attn, w_proj, xb,
                                                wt_attn, wt_proj);
  gemm_qkv<<<dim3(N3_ / GBN, M_ / GBM), 512, 0, stream>>>(xb, wt_attn, qb, kb,
                                                          vst);
  attn128<<<B_ * H_ * (T_ / 128), 256, 0, stream>>>(qb, kb, vst, yb);
  gemm_proj<<<dim3(D_ / PBN, M_ / PBM), 512, 0, stream>>>(yb, wt_proj, out);
}